// Round 6
// baseline (350.157 us; speedup 1.0000x reference)
//
#include <hip/hip_runtime.h>

#define NN 512
#define CCH 128
#define MM (NN*NN)   // 262144

using f32x4  = __attribute__((ext_vector_type(4))) float;
using f32x2  = __attribute__((ext_vector_type(2))) float;
using bf16x8 = __attribute__((ext_vector_type(8))) short;
using u16x4  = __attribute__((ext_vector_type(4))) unsigned short;
using u32x2  = __attribute__((ext_vector_type(2))) unsigned int;
using u32x4  = __attribute__((ext_vector_type(4))) unsigned int;
typedef unsigned short u16;

__device__ __forceinline__ u16 f2bf(float f) {
    unsigned u = __builtin_bit_cast(unsigned, f);
    u += 0x7FFF + ((u >> 16) & 1);
    return (u16)(u >> 16);
}
__device__ __forceinline__ float bf2f(u16 h) {
    unsigned u = ((unsigned)h) << 16;
    return __builtin_bit_cast(float, u);
}
// pack 2 f32 -> 2 bf16 (RNE), lo = first arg  (proven bit-twiddle, NOT cvt_pk asm)
__device__ __forceinline__ unsigned pack2(float lo, float hi) {
    return (unsigned)f2bf(lo) | ((unsigned)f2bf(hi) << 16);
}
__device__ __forceinline__ float sigm(float x) { return 1.0f / (1.0f + __expf(-x)); }

__device__ __forceinline__ void gl_lds16(const void* g, void* l) {
    __builtin_amdgcn_global_load_lds(
        (const __attribute__((address_space(1))) void*)g,
        (__attribute__((address_space(3))) void*)l, 16, 0, 0);
}

// ---------------- k_prep: fold LN gamma/beta into bf16 weights + biases ----
// Weight rows stored CHUNK-SWIZZLED: logical 16B chunk q of row o lives at
// physical chunk (q ^ (o&7)).
__global__ __launch_bounds__(256) void k_prep(
    const float* __restrict__ w0, const float* __restrict__ w1,
    const float* __restrict__ w2, const float* __restrict__ w3,
    const float* __restrict__ w4, const float* __restrict__ w5,
    const float* __restrict__ b0, const float* __restrict__ b1,
    const float* __restrict__ b2, const float* __restrict__ b3,
    const float* __restrict__ b4, const float* __restrict__ b5,
    const float* __restrict__ gin, const float* __restrict__ bin,
    const float* __restrict__ gout, const float* __restrict__ bout,
    u16* __restrict__ wbf, float* __restrict__ bias2) {
    int mat = blockIdx.x;
    const float* W = mat==0?w0:mat==1?w1:mat==2?w2:mat==3?w3:mat==4?w4:w5;
    const float* B = mat==0?b0:mat==1?b1:mat==2?b2:mat==3?b3:mat==4?b4:b5;
    const float* G = (mat==5)? gout : gin;
    const float* Bt= (mat==5)? bout : bin;
    __shared__ float gs[CCH], bs[CCH];
    int tid = threadIdx.x;
    if (tid < CCH) { gs[tid] = G[tid]; bs[tid] = Bt[tid]; }
    __syncthreads();
    int o = tid >> 1, c0 = (tid & 1) * 64;
    const float* src = W + o * CCH + c0;
    char* dstrow = (char*)(wbf + mat * 16384) + o * 256;
    int key = o & 7;
    float dot = 0.f;
    #pragma unroll
    for (int q = 0; q < 16; ++q) {
        f32x4 v = *(const f32x4*)(src + q * 4);
        int c = c0 + q * 4;
        dot += bs[c]*v.x + bs[c+1]*v.y + bs[c+2]*v.z + bs[c+3]*v.w;
        u16x4 p;
        p.x = f2bf(v.x * gs[c]);     p.y = f2bf(v.y * gs[c+1]);
        p.z = f2bf(v.z * gs[c+2]);   p.w = f2bf(v.w * gs[c+3]);
        int chunk = (c0 >> 3) + (q >> 1);
        *(u16x4*)(dstrow + (((chunk ^ key)) << 4) + ((q & 1) << 3)) = p;
    }
    dot += __shfl_xor(dot, 1);
    if ((tid & 1) == 0) bias2[mat * CCH + o] = B[o] + dot;
}

// ---------------- k_ln: LN(z) -> zn (bf16, odd 256B halves of d_out) ------
__global__ __launch_bounds__(256) void k_ln(const float* __restrict__ z,
                                            u16* __restrict__ dz) {
    int tid = threadIdx.x;
    int w = tid >> 6, lane = tid & 63;
    long row = (long)blockIdx.x * 4 + w;
    f32x2 v = *(const f32x2*)(z + row * CCH + lane * 2);
    float s = v.x + v.y, s2 = v.x * v.x + v.y * v.y;
    #pragma unroll
    for (int off = 32; off; off >>= 1) {
        s  += __shfl_xor(s, off);
        s2 += __shfl_xor(s2, off);
    }
    float mu  = s * (1.0f / CCH);
    float var = fmaxf(s2 * (1.0f / CCH) - mu * mu, 0.f);
    float rs  = rsqrtf(var + 1e-5f);
    unsigned pk = pack2((v.x - mu) * rs, (v.y - mu) * rs);
    *(unsigned*)(dz + row * 256 + 128 + lane * 2) = pk;
}

// ---------------- k_proj: one projection per block -------------------------
// grid (4096 m-blocks, 2 ch-halves, 3 modes). mode 0: a-pair -> aT;
// mode 1: b-pair -> bT; mode 2: gate -> even row-halves of d_out.
// All outputs stored DIRECTLY from accumulators (no LDS transpose).
__global__ __launch_bounds__(256, 4) void k_proj(
    const u16* dz, const float* __restrict__ mask,
    const u16* __restrict__ wbf, const float* __restrict__ bias2,
    u16* __restrict__ aT, u16* __restrict__ bT) {
    __shared__ __align__(16) u16 w1s[8192];   // 16KB: 64 rows x 256B (swizzled)
    __shared__ __align__(16) u16 w2s[8192];
    int tid = threadIdx.x, w = tid >> 6, lane = tid & 63;
    int r = lane & 15, kq = lane >> 4;
    long m0 = (long)blockIdx.x * 64;
    int ch = blockIdx.y, mode = blockIdx.z;
    int i7 = (int)((m0 >> 9) & 7);
    int mat1 = (mode == 2) ? 4 : mode * 2;

    const char* W1g = (const char*)wbf + (size_t)(mat1 * 16384 + ch * 64 * CCH) * 2;
    const char* W2g = (const char*)wbf + (size_t)((mat1 + 1) * 16384 + ch * 64 * CCH) * 2;
    #pragma unroll
    for (int it = 0; it < 4; ++it) {
        long off = (long)it * 4096 + tid * 16;
        gl_lds16(W1g + off, (char*)w1s + it * 4096 + w * 1024);
        if (mode < 2) gl_lds16(W2g + off, (char*)w2s + it * 4096 + w * 1024);
    }

    // A-fragments from zn (global, bf16)
    bf16x8 av[4];
    long mrow = m0 + w * 16 + r;
    #pragma unroll
    for (int kb = 0; kb < 4; ++kb)
        av[kb] = *(const bf16x8*)(dz + mrow * 256 + 128 + kb * 32 + kq * 8);

    f32x4 mkv = {1.f, 1.f, 1.f, 1.f};
    if (mode < 2) mkv = *(const f32x4*)(mask + m0 + w * 16 + kq * 4);

    __syncthreads();

    if (mode < 2) {
        // mfma(zn, W): j-regs -> 4 consecutive m; col r -> out channel
        f32x4 acc1[4], acc2[4];
        #pragma unroll
        for (int nt = 0; nt < 4; ++nt) { acc1[nt] = {0,0,0,0}; acc2[nt] = {0,0,0,0}; }
        #pragma unroll
        for (int nt = 0; nt < 4; ++nt) {
            int ol = nt * 16 + r;
            int key = ol & 7;
            const char* row1 = (const char*)w1s + ol * 256;
            const char* row2 = (const char*)w2s + ol * 256;
            #pragma unroll
            for (int kb = 0; kb < 4; ++kb) {
                int ph = ((kb * 4 + kq) ^ key) << 4;
                bf16x8 b1 = *(const bf16x8*)(row1 + ph);
                bf16x8 b2 = *(const bf16x8*)(row2 + ph);
                acc1[nt] = __builtin_amdgcn_mfma_f32_16x16x32_bf16(av[kb], b1, acc1[nt], 0, 0, 0);
                acc2[nt] = __builtin_amdgcn_mfma_f32_16x16x32_bf16(av[kb], b2, acc2[nt], 0, 0, 0);
            }
        }
        u16* dst = mode ? bT : aT;
        int q = w * 2 + (kq >> 1);                 // chunk within 128B m-group
        long boff = m0 * 2 + (long)((q ^ i7) << 4) + ((kq & 1) << 3);
        #pragma unroll
        for (int nt = 0; nt < 4; ++nt) {
            int cc = nt * 16 + r;
            float b1v = bias2[mat1 * CCH + ch * 64 + cc];
            float b2v = bias2[(mat1 + 1) * CCH + ch * 64 + cc];
            float v0 = mkv[0] * sigm(acc1[nt][0] + b1v) * (acc2[nt][0] + b2v);
            float v1 = mkv[1] * sigm(acc1[nt][1] + b1v) * (acc2[nt][1] + b2v);
            float v2 = mkv[2] * sigm(acc1[nt][2] + b1v) * (acc2[nt][2] + b2v);
            float v3 = mkv[3] * sigm(acc1[nt][3] + b1v) * (acc2[nt][3] + b2v);
            u32x2 pv; pv.x = pack2(v0, v1); pv.y = pack2(v2, v3);
            *(u32x2*)((char*)(dst + (long)(ch * 64 + cc) * MM) + boff) = pv;
        }
    } else {
        // gate: mfma(W, zn): j-regs -> 4 consecutive c; col r -> m-row
        f32x4 acc[4];
        #pragma unroll
        for (int nt = 0; nt < 4; ++nt) acc[nt] = {0,0,0,0};
        #pragma unroll
        for (int nt = 0; nt < 4; ++nt) {
            int ol = nt * 16 + r;
            int key = ol & 7;
            const char* row1 = (const char*)w1s + ol * 256;
            #pragma unroll
            for (int kb = 0; kb < 4; ++kb) {
                bf16x8 b1 = *(const bf16x8*)(row1 + (((kb * 4 + kq) ^ key) << 4));
                acc[nt] = __builtin_amdgcn_mfma_f32_16x16x32_bf16(b1, av[kb], acc[nt], 0, 0, 0);
            }
        }
        long m = m0 + w * 16 + r;
        #pragma unroll
        for (int nt = 0; nt < 4; ++nt) {
            int c0 = nt * 16 + kq * 4;
            f32x4 bg = *(const f32x4*)(bias2 + 4 * CCH + ch * 64 + c0);
            u32x2 pv;
            pv.x = pack2(sigm(acc[nt][0] + bg[0]), sigm(acc[nt][1] + bg[1]));
            pv.y = pack2(sigm(acc[nt][2] + bg[2]), sigm(acc[nt][3] + bg[3]));
            *(u32x2*)(dz + m * 256 + ch * 64 + c0) = pv;
        }
    }
}

// ---------------- k_tri: per-channel triangle GEMM, BK=64 ------------------
// swapped mfma: j-regs -> 4 consecutive j-columns -> packed 8B stores
__global__ __launch_bounds__(256, 4) void k_tri(const u16* __restrict__ aT,
                                                const u16* __restrict__ bT,
                                                u16* __restrict__ xT) {
    __shared__ __align__(16) u16 At[128 * 64];  // 16KB
    __shared__ __align__(16) u16 Bt[128 * 64];
    int tid = threadIdx.x;
    int w = tid >> 6, lane = tid & 63;
    int r = lane & 15, kq = lane >> 4;

    int L = blockIdx.x;
    int xcd = L & 7, idx = L >> 3;
    int c    = xcd + 8 * (idx >> 4);
    int tile = idx & 15;
    int ti = tile >> 2, tj = tile & 3;

    const char* abase = (const char*)(aT + (long)c * MM) + (long)(ti * 128) * 1024;
    const char* bbase = (const char*)(bT + (long)c * MM) + (long)(tj * 128) * 1024;
    int wm = w >> 1, wn = w & 1;

    f32x4 acc[4][4];
    #pragma unroll
    for (int a = 0; a < 4; ++a)
        #pragma unroll
        for (int bq = 0; bq < 4; ++bq) acc[a][bq] = {0.f,0.f,0.f,0.f};

    for (int ks = 0; ks < 8; ++ks) {
        const char* asrc = abase + ks * 128;
        const char* bsrc = bbase + ks * 128;
        #pragma unroll
        for (int it = 0; it < 4; ++it) {
            int u = it * 256 + tid;
            long goff = (long)(u >> 3) * 1024 + (u & 7) * 16;
            gl_lds16(asrc + goff, (char*)At + it * 4096 + w * 1024);
            gl_lds16(bsrc + goff, (char*)Bt + it * 4096 + w * 1024);
        }
        __syncthreads();

        #pragma unroll
        for (int kh = 0; kh < 2; ++kh) {
            bf16x8 af[4];
            #pragma unroll
            for (int mt = 0; mt < 4; ++mt) {
                int rowa = wm * 64 + mt * 16 + r;
                af[mt] = *(const bf16x8*)((const char*)At + rowa * 128 +
                                          (((kh * 4 + kq) ^ (r & 7)) << 4));
            }
            #pragma unroll
            for (int nt = 0; nt < 4; ++nt) {
                int rowb = wn * 64 + nt * 16 + r;
                bf16x8 bf = *(const bf16x8*)((const char*)Bt + rowb * 128 +
                                             (((kh * 4 + kq) ^ (r & 7)) << 4));
                #pragma unroll
                for (int mt = 0; mt < 4; ++mt)
                    acc[mt][nt] = __builtin_amdgcn_mfma_f32_16x16x32_bf16(bf, af[mt], acc[mt][nt], 0, 0, 0);
            }
        }
        __syncthreads();
    }

    // col r = i-row, j-regs = consecutive j
    u16* xbase = xT + (long)c * MM;
    int gi0 = ti * 128 + wm * 64;
    int gj0 = tj * 128 + wn * 64;
    #pragma unroll
    for (int mt = 0; mt < 4; ++mt) {
        long row = gi0 + mt * 16 + r;
        #pragma unroll
        for (int nt = 0; nt < 4; ++nt) {
            int col = gj0 + nt * 16 + kq * 4;
            u32x2 pv;
            pv.x = pack2(acc[mt][nt][0], acc[mt][nt][1]);
            pv.y = pack2(acc[mt][nt][2], acc[mt][nt][3]);
            *(u32x2*)(xbase + row * NN + col) = pv;
        }
    }
}

// ---------------- k_out: LN(x) @ w_z''^T + bias2_z, * gate -----------------
// swapped mfma: j-regs -> 4 consecutive c -> f32x4 stores
__global__ __launch_bounds__(256, 4) void k_out(const u16* __restrict__ xT,
                                                const u16* __restrict__ wbf,
                                                const float* __restrict__ bias2,
                                                const u16* gateB,
                                                float* __restrict__ outp) {
    __shared__ __align__(16) u16 xl[64 * 128];  // 16KB
    int tid = threadIdx.x, w = tid >> 6, lane = tid & 63;
    int r = lane & 15, kq = lane >> 4;
    long m0 = (long)blockIdx.x * 64;

    // transpose stage: xT[c][m] -> xl[m][c], 4 channels packed per u16x4
    {
        int cg = tid & 31, ms = tid >> 5;
        int c0 = cg * 4;
        const u16* base = xT + m0 + (long)ms * 8;
        bf16x8 v0 = *(const bf16x8*)(base + (long)(c0 + 0) * MM);
        bf16x8 v1 = *(const bf16x8*)(base + (long)(c0 + 1) * MM);
        bf16x8 v2 = *(const bf16x8*)(base + (long)(c0 + 2) * MM);
        bf16x8 v3 = *(const bf16x8*)(base + (long)(c0 + 3) * MM);
        #pragma unroll
        for (int e = 0; e < 8; ++e) {
            int m = ms * 8 + e;
            u16x4 t;
            t.x = (u16)v0[e]; t.y = (u16)v1[e]; t.z = (u16)v2[e]; t.w = (u16)v3[e];
            *(u16x4*)((char*)xl + m * 256 + ((c0 * 2) ^ ((m & 15) << 4))) = t;
        }
    }
    __syncthreads();

    // A-frags as u32 pairs + LN stats via mask/shift decode
    int mlr = w * 16 + r;
    int swm = (mlr & 15) << 4;
    u32x4 avu[4];
    float s = 0.f, s2 = 0.f;
    #pragma unroll
    for (int kb = 0; kb < 4; ++kb) {
        avu[kb] = *(const u32x4*)((const char*)xl + mlr * 256 + ((kb * 64 + kq * 16) ^ swm));
        #pragma unroll
        for (int p = 0; p < 4; ++p) {
            unsigned u = avu[kb][p];
            float flo = __builtin_bit_cast(float, u << 16);
            float fhi = __builtin_bit_cast(float, u & 0xFFFF0000u);
            s += flo + fhi;
            s2 = fmaf(flo, flo, s2);
            s2 = fmaf(fhi, fhi, s2);
        }
    }
    s  += __shfl_xor(s, 16);  s  += __shfl_xor(s, 32);
    s2 += __shfl_xor(s2, 16); s2 += __shfl_xor(s2, 32);
    float mu = s * (1.0f / CCH);
    float var = fmaxf(s2 * (1.0f / CCH) - mu * mu, 0.f);
    float rs = rsqrtf(var + 1e-5f);
    float nmu = -mu * rs;
    bf16x8 av[4];
    #pragma unroll
    for (int kb = 0; kb < 4; ++kb) {
        u32x4 o;
        #pragma unroll
        for (int p = 0; p < 4; ++p) {
            unsigned u = avu[kb][p];
            float flo = __builtin_bit_cast(float, u << 16);
            float fhi = __builtin_bit_cast(float, u & 0xFFFF0000u);
            o[p] = pack2(fmaf(flo, rs, nmu), fmaf(fhi, rs, nmu));
        }
        av[kb] = __builtin_bit_cast(bf16x8, o);
    }

    // gate preload (gateB aliases outp rows of THIS block only)
    long m = m0 + w * 16 + r;
    u16x4 gvu[8];
    #pragma unroll
    for (int nt = 0; nt < 8; ++nt)
        gvu[nt] = *(const u16x4*)(gateB + m * 256 + nt * 16 + kq * 4);

    // swapped MFMA vs w_z'' (global reads, chunk-swizzled layout)
    const char* Wz = (const char*)(wbf + 5 * 16384);
    f32x4 acc[8];
    #pragma unroll
    for (int nt = 0; nt < 8; ++nt) acc[nt] = {0,0,0,0};
    #pragma unroll
    for (int nt = 0; nt < 8; ++nt) {
        int ol = nt * 16 + r;
        int key = ol & 7;
        const char* row = Wz + ol * 256;
        #pragma unroll
        for (int kb = 0; kb < 4; ++kb) {
            bf16x8 bw = *(const bf16x8*)(row + (((kb * 4 + kq) ^ key) << 4));
            acc[nt] = __builtin_amdgcn_mfma_f32_16x16x32_bf16(bw, av[kb], acc[nt], 0, 0, 0);
        }
    }

    __syncthreads();   // ALL gate loads done before any aliasing store

    const float* b2z = bias2 + 5 * CCH;
    #pragma unroll
    for (int nt = 0; nt < 8; ++nt) {
        int c0 = nt * 16 + kq * 4;
        f32x4 bb = *(const f32x4*)(b2z + c0);
        f32x4 o;
        #pragma unroll
        for (int j = 0; j < 4; ++j)
            o[j] = (acc[nt][j] + bb[j]) * bf2f(gvu[nt][j]);
        *(f32x4*)(outp + m * CCH + c0) = o;
    }
}

extern "C" void kernel_launch(void* const* d_in, const int* in_sizes, int n_in,
                              void* d_out, int out_size, void* d_ws, size_t ws_size,
                              hipStream_t stream) {
    const float* z       = (const float*)d_in[0];
    const float* mask    = (const float*)d_in[1];
    const float* ln_in_g = (const float*)d_in[2];
    const float* ln_in_b = (const float*)d_in[3];
    const float* w_ag    = (const float*)d_in[4];
    const float* b_ag    = (const float*)d_in[5];
    const float* w_ap    = (const float*)d_in[6];
    const float* b_ap    = (const float*)d_in[7];
    const float* w_bg    = (const float*)d_in[8];
    const float* b_bg    = (const float*)d_in[9];
    const float* w_bp    = (const float*)d_in[10];
    const float* b_bp    = (const float*)d_in[11];
    const float* w_g     = (const float*)d_in[12];
    const float* b_g     = (const float*)d_in[13];
    const float* w_z     = (const float*)d_in[14];
    const float* b_z     = (const float*)d_in[15];
    const float* ln_o_g  = (const float*)d_in[16];
    const float* ln_o_b  = (const float*)d_in[17];
    float* out = (float*)d_out;
    u16* dz = (u16*)d_out;   // row m: gate bf16 at u16[0,128), zn bf16 at u16[128,256)

    char* ws = (char*)d_ws;
    const size_t SL = (size_t)MM * CCH * 2;  // 64MB per slot
    u16* xT   = (u16*)ws;
    u16* aT   = (u16*)(ws + SL);
    u16* bT   = (u16*)(ws + 2 * SL);
    u16* wbf  = (u16*)(ws + 3 * SL);                       // 192KB swizzled bf16 weights
    float* b2 = (float*)(ws + 3 * SL + 6 * 16384 * 2);     // 3KB folded biases

    k_prep<<<6, 256, 0, stream>>>(w_ag, w_ap, w_bg, w_bp, w_g, w_z,
                                  b_ag, b_ap, b_bg, b_bp, b_g, b_z,
                                  ln_in_g, ln_in_b, ln_o_g, ln_o_b, wbf, b2);
    k_ln<<<MM / 4, 256, 0, stream>>>(z, dz);
    k_proj<<<dim3(MM / 64, 2, 3), 256, 0, stream>>>(dz, mask, wbf, b2, aT, bT);
    k_tri<<<2048, 256, 0, stream>>>(aT, bT, xT);
    k_out<<<MM / 64, 256, 0, stream>>>(xT, wbf, b2, dz, out);
}